// Round 4
// baseline (2582.315 us; speedup 1.0000x reference)
//
#include <hip/hip_runtime.h>
#include <hip/hip_bf16.h>

// BeitSelfAttention — diagnosis round: per-region (Q/K/V) check flags + gated
// per-region repair kernels. Region-set decodable from total dur via spin
// offsets (K:+40us, V:+80us). gemm_qkv (triple-split MFMA), attention kernels
// verbatim from previous round.
// Evidence so far: check fires even with triple-split (~1e-5 error) at 2e-3
// threshold -> gemm_qkv output is STRUCTURALLY wrong somewhere; repair's f32
// (tile64) output is ground truth (harness passes when it overwrites).
// Shapes: B=8 S=1569 D=768 NH=12 DH=64 NCLS=1 BS=49 M=32 NKV=6

#define S_TOT   1569
#define NCOL    2304          // 3*768
#define NBATCH  8
#define NX      9637632       // 8*1569*768

typedef __attribute__((ext_vector_type(8))) short bf16x8;   // 8 bf16 (4 VGPRs)
typedef __attribute__((ext_vector_type(4))) float f32x4;
typedef unsigned short u16;

static __device__ __forceinline__ u16 f2bf(float x) {
    __hip_bfloat16 b = __float2bfloat16(x);
    return *reinterpret_cast<u16*>(&b);
}
static __device__ __forceinline__ float bf2f(u16 u) {
    __hip_bfloat16 b;
    *reinterpret_cast<u16*>(&b) = u;
    return __bfloat162float(b);
}

// dependent-FMA spin: iters * ~4cyc; 24000 iters ~ 40us @2.4GHz
static __device__ __forceinline__ void spin_fma(int iters) {
    float x = (float)threadIdx.x;
    for (int i = 0; i < iters; i++) x = fmaf(x, 0.9999f, 1e-6f);
    asm volatile("" :: "v"(x));
}

__global__ void init_flag(int* flag) { *flag = 0; }

// -------- conv_x: hs f32 -> Xhi = bf16(x), Xlo = bf16(x - Xhi)
__global__ __launch_bounds__(256) void conv_x(const float* __restrict__ hs,
                                              u16* __restrict__ Xhi,
                                              u16* __restrict__ Xlo) {
    int v = blockIdx.x * 256 + threadIdx.x;     // 8-element group index
    if (v >= NX / 8) return;
    const float4* src = (const float4*)hs + 2 * (size_t)v;
    float4 x0 = src[0], x1 = src[1];
    float xs[8] = {x0.x, x0.y, x0.z, x0.w, x1.x, x1.y, x1.z, x1.w};
    u16 hi[8], lo[8];
#pragma unroll
    for (int i = 0; i < 8; i++) {
        u16 hb = f2bf(xs[i]);
        hi[i] = hb;
        lo[i] = f2bf(xs[i] - bf2f(hb));
    }
    uint4 hv, lv;
    hv.x = hi[0] | ((unsigned)hi[1] << 16);  hv.y = hi[2] | ((unsigned)hi[3] << 16);
    hv.z = hi[4] | ((unsigned)hi[5] << 16);  hv.w = hi[6] | ((unsigned)hi[7] << 16);
    lv.x = lo[0] | ((unsigned)lo[1] << 16);  lv.y = lo[2] | ((unsigned)lo[3] << 16);
    lv.z = lo[4] | ((unsigned)lo[5] << 16);  lv.w = lo[6] | ((unsigned)lo[7] << 16);
    ((uint4*)Xhi)[v] = hv;
    ((uint4*)Xlo)[v] = lv;
}

// -------- conv_w2: W (768x768 f32 x3) -> Wtf f32 (2304x768, W^T), Whi bf16, Wlo bf16
__global__ __launch_bounds__(256) void conv_w2(const float* __restrict__ Wq,
                                               const float* __restrict__ Wk,
                                               const float* __restrict__ Wv,
                                               float* __restrict__ Wtf,
                                               u16* __restrict__ Whi,
                                               u16* __restrict__ Wlo) {
    __shared__ float tile[32][33];
    int n0 = blockIdx.x * 32;
    int d0 = blockIdx.y * 32;
    int tx = threadIdx.x & 31, ty = threadIdx.x >> 5;
    int which = n0 / 768;
    int nn0 = n0 - which * 768;
    const float* W = (which == 0) ? Wq : (which == 1 ? Wk : Wv);
#pragma unroll
    for (int k = 0; k < 4; k++)
        tile[ty + 8 * k][tx] = W[(d0 + ty + 8 * k) * 768 + nn0 + tx];
    __syncthreads();
#pragma unroll
    for (int k = 0; k < 4; k++) {
        float v = tile[tx][ty + 8 * k];
        int idx = (n0 + ty + 8 * k) * 768 + d0 + tx;
        Wtf[idx] = v;
        u16 hb = f2bf(v);
        Whi[idx] = hb;
        Wlo[idx] = f2bf(v - bf2f(hb));
    }
}

// -------- gemm_qkv: triple-split bf16 MFMA GEMM -> Q,K,V f32 (unchanged)
__global__ __launch_bounds__(256, 2) void gemm_qkv(const u16* __restrict__ Xhi,
                                                   const u16* __restrict__ Xlo,
                                                   const u16* __restrict__ Whi,
                                                   const u16* __restrict__ Wlo,
                                                   const float* __restrict__ bq,
                                                   const float* __restrict__ bv,
                                                   float* __restrict__ Q,
                                                   float* __restrict__ K,
                                                   float* __restrict__ V,
                                                   int b0, int nTok) {
    __shared__ u16 Ah[128][72];
    __shared__ u16 Al[128][72];
    __shared__ u16 Bh[128][72];
    __shared__ u16 Bl[128][72];
    int tid = threadIdx.x;
    int t0 = blockIdx.x * 128;
    int n0 = blockIdx.y * 128;
    int lane = tid & 63, w = tid >> 6;
    int wr = (w >> 1) * 64, wc = (w & 1) * 64;
    int lm = lane & 15, lq = lane >> 4;
    int srow = tid >> 3;
    int svec = (tid & 7) * 8;
    const u16* Xhb = Xhi + (size_t)b0 * S_TOT * 768;
    const u16* Xlb = Xlo + (size_t)b0 * S_TOT * 768;

    f32x4 acc[4][4];
#pragma unroll
    for (int mi = 0; mi < 4; mi++)
#pragma unroll
        for (int ni = 0; ni < 4; ni++)
            acc[mi][ni] = (f32x4){0.f, 0.f, 0.f, 0.f};

    for (int k0 = 0; k0 < 768; k0 += 64) {
#pragma unroll
        for (int g = 0; g < 4; g++) {
            int r = srow + g * 32;
            int t = t0 + r;
            uint4 hv = make_uint4(0u, 0u, 0u, 0u);
            uint4 lv = make_uint4(0u, 0u, 0u, 0u);
            if (t < nTok) {
                hv = *(const uint4*)(Xhb + (size_t)t * 768 + k0 + svec);
                lv = *(const uint4*)(Xlb + (size_t)t * 768 + k0 + svec);
            }
            *(uint4*)&Ah[r][svec] = hv;
            *(uint4*)&Al[r][svec] = lv;
            *(uint4*)&Bh[r][svec] = *(const uint4*)(Whi + (n0 + r) * 768 + k0 + svec);
            *(uint4*)&Bl[r][svec] = *(const uint4*)(Wlo + (n0 + r) * 768 + k0 + svec);
        }
        __syncthreads();
#pragma unroll
        for (int ks = 0; ks < 64; ks += 32) {
            bf16x8 ah[4], al[4], bh[4], blo[4];
#pragma unroll
            for (int mi = 0; mi < 4; mi++) {
                ah[mi] = *(const bf16x8*)&Ah[wr + mi * 16 + lm][ks + lq * 8];
                al[mi] = *(const bf16x8*)&Al[wr + mi * 16 + lm][ks + lq * 8];
            }
#pragma unroll
            for (int ni = 0; ni < 4; ni++) {
                bh[ni]  = *(const bf16x8*)&Bh[wc + ni * 16 + lm][ks + lq * 8];
                blo[ni] = *(const bf16x8*)&Bl[wc + ni * 16 + lm][ks + lq * 8];
            }
#pragma unroll
            for (int mi = 0; mi < 4; mi++)
#pragma unroll
                for (int ni = 0; ni < 4; ni++) {
                    acc[mi][ni] = __builtin_amdgcn_mfma_f32_16x16x32_bf16(ah[mi], bh[ni],  acc[mi][ni], 0, 0, 0);
                    acc[mi][ni] = __builtin_amdgcn_mfma_f32_16x16x32_bf16(ah[mi], blo[ni], acc[mi][ni], 0, 0, 0);
                    acc[mi][ni] = __builtin_amdgcn_mfma_f32_16x16x32_bf16(al[mi], bh[ni],  acc[mi][ni], 0, 0, 0);
                }
        }
        __syncthreads();
    }

    // epilogue: D[row=(lane>>4)*4+r][col=lane&15]  (m89/m91-verified)
#pragma unroll
    for (int mi = 0; mi < 4; mi++) {
#pragma unroll
        for (int ni = 0; ni < 4; ni++) {
            int n = n0 + wc + ni * 16 + lm;
#pragma unroll
            for (int r = 0; r < 4; r++) {
                int t = t0 + wr + mi * 16 + lq * 4 + r;
                if (t >= nTok) continue;
                float val = acc[mi][ni][r];
                float* dst;
                int nn;
                if (n < 768)       { dst = Q; nn = n;        val += bq[nn]; }
                else if (n < 1536) { dst = K; nn = n - 768;                 }
                else               { dst = V; nn = n - 1536; val += bv[nn]; }
                int bl = t / S_TOT;
                int s = t - bl * S_TOT;
                int h = nn >> 6, d = nn & 63;
                dst[((bl * 12 + h) * S_TOT + s) * 64 + d] = val;
            }
        }
    }
}

// -------- shared f32 64x64 tile compute (XOR-swizzled LDS)
static __device__ __forceinline__ void tile64_compute(const float* __restrict__ Xb,
                                                      const float* __restrict__ Wtf,
                                                      int t0, int n0, int nTok,
                                                      float (*Xs)[72], float (*Ws)[72],
                                                      float acc[4][4]) {
    int tid = threadIdx.x;
    int ty = tid >> 4, tx = tid & 15;
    int sr = tid >> 2;
    int sc = (tid & 3) * 4;
#pragma unroll
    for (int ii = 0; ii < 4; ii++)
#pragma unroll
        for (int jj = 0; jj < 4; jj++) acc[ii][jj] = 0.f;

    for (int k0 = 0; k0 < 768; k0 += 64) {
#pragma unroll
        for (int i = 0; i < 4; i++) {
            int c4 = sc + i;                     // logical col-group 0..15
            int c4s = c4 ^ (sr >> 2);            // swizzled store col-group
            float4 xv = make_float4(0.f, 0.f, 0.f, 0.f);
            if (t0 + sr < nTok)
                xv = *(const float4*)(Xb + (size_t)(t0 + sr) * 768 + k0 + c4 * 4);
            *(float4*)&Xs[sr][c4s * 4] = xv;
            *(float4*)&Ws[sr][c4s * 4] = *(const float4*)(Wtf + (size_t)(n0 + sr) * 768 + k0 + c4 * 4);
        }
        __syncthreads();
#pragma unroll
        for (int k4 = 0; k4 < 16; k4++) {
            float4 xa[4], wb[4];
#pragma unroll
            for (int ii = 0; ii < 4; ii++) {
                int R = ty * 4 + ii;
                xa[ii] = *(const float4*)&Xs[R][(k4 ^ (R >> 2)) * 4];
            }
#pragma unroll
            for (int jj = 0; jj < 4; jj++) {
                int R = tx * 4 + jj;
                wb[jj] = *(const float4*)&Ws[R][(k4 ^ (R >> 2)) * 4];
            }
#pragma unroll
            for (int ii = 0; ii < 4; ii++)
#pragma unroll
                for (int jj = 0; jj < 4; jj++) {
                    acc[ii][jj] = fmaf(xa[ii].x, wb[jj].x, acc[ii][jj]);
                    acc[ii][jj] = fmaf(xa[ii].y, wb[jj].y, acc[ii][jj]);
                    acc[ii][jj] = fmaf(xa[ii].z, wb[jj].z, acc[ii][jj]);
                    acc[ii][jj] = fmaf(xa[ii].w, wb[jj].w, acc[ii][jj]);
                }
        }
        __syncthreads();
    }
}

static __device__ __forceinline__ int qkv_index(int n, int t, float* Q, float* K, float* V,
                                                const float* bq, const float* bv,
                                                float** dstOut, float* biasOut) {
    float* dst; int nn; float bias = 0.f;
    if (n < 768)       { dst = Q; nn = n;        bias = bq[nn]; }
    else if (n < 1536) { dst = K; nn = n - 768;                 }
    else               { dst = V; nn = n - 1536; bias = bv[nn]; }
    int bl = t / S_TOT;
    int s = t - bl * S_TOT;
    *dstOut = dst; *biasOut = bias;
    return ((bl * 12 + (nn >> 6)) * S_TOT + s) * 64 + (nn & 63);
}

// -------- check_gemm: 6 slabs x 64 tokens f32 recompute; per-REGION flag bits
__global__ __launch_bounds__(256) void check_gemm(const float* __restrict__ hs,
                                                  const float* __restrict__ Wtf,
                                                  const float* __restrict__ bq,
                                                  const float* __restrict__ bv,
                                                  float* __restrict__ Q,
                                                  float* __restrict__ K,
                                                  float* __restrict__ V,
                                                  int b0, int nTok,
                                                  int* __restrict__ flag) {
    __shared__ float Xs[64][72];
    __shared__ float Ws[64][72];
    int si = blockIdx.x;
    int t0;
    if (si < 2)      t0 = si * 64;
    else if (si < 4) t0 = ((nTok / 2 - 64) & ~63) + (si - 2) * 64;
    else             t0 = nTok - 128 + (si - 4) * 64;
    int n0 = blockIdx.y * 64;
    int region = n0 / 768;               // 0=Q 1=K 2=V (64-col stripe, single region)
    const float* Xb = hs + (size_t)b0 * S_TOT * 768;
    float acc[4][4];
    tile64_compute(Xb, Wtf, t0, n0, nTok, Xs, Ws, acc);

    int ty = threadIdx.x >> 4, tx = threadIdx.x & 15;
    int bad = 0;
#pragma unroll
    for (int ii = 0; ii < 4; ii++) {
#pragma unroll
        for (int jj = 0; jj < 4; jj++) {
            int t = t0 + ty * 4 + ii;
            int n = n0 + tx * 4 + jj;
            float* dst; float bias;
            int idx = qkv_index(n, t, Q, K, V, bq, bv, &dst, &bias);
            float expect = acc[ii][jj] + bias;
            if (fabsf(expect - dst[idx]) > 2e-3f) bad = 1;   // triple-split noise ~1e-5
        }
    }
    if (bad) atomicOr(flag, 1 << region);
}

// -------- per-region repair: f32 tiled GEMM over one 768-col region, gated on bit
static __device__ __forceinline__ void repair_region(const float* __restrict__ hs,
                                                     const float* __restrict__ Wtf,
                                                     const float* __restrict__ bq,
                                                     const float* __restrict__ bv,
                                                     float* __restrict__ Q,
                                                     float* __restrict__ K,
                                                     float* __restrict__ V,
                                                     int b0, int nTok, int reg) {
    __shared__ float Xs[64][72];
    __shared__ float Ws[64][72];
    int t0 = blockIdx.x * 64;
    int n0 = reg * 768 + blockIdx.y * 64;
    const float* Xb = hs + (size_t)b0 * S_TOT * 768;
    float acc[4][4];
    tile64_compute(Xb, Wtf, t0, n0, nTok, Xs, Ws, acc);

    int ty = threadIdx.x >> 4, tx = threadIdx.x & 15;
#pragma unroll
    for (int ii = 0; ii < 4; ii++) {
#pragma unroll
        for (int jj = 0; jj < 4; jj++) {
            int t = t0 + ty * 4 + ii;
            if (t >= nTok) continue;
            int n = n0 + tx * 4 + jj;
            float* dst; float bias;
            int idx = qkv_index(n, t, Q, K, V, bq, bv, &dst, &bias);
            dst[idx] = acc[ii][jj] + bias;
        }
    }
}

__global__ __launch_bounds__(256) void repair_q(const float* __restrict__ hs,
                                                const float* __restrict__ Wtf,
                                                const float* __restrict__ bq,
                                                const float* __restrict__ bv,
                                                float* Q, float* K, float* V,
                                                int b0, int nTok,
                                                const int* __restrict__ flag) {
    if (!((*flag) & 1)) return;
    repair_region(hs, Wtf, bq, bv, Q, K, V, b0, nTok, 0);
}
__global__ __launch_bounds__(256) void repair_k(const float* __restrict__ hs,
                                                const float* __restrict__ Wtf,
                                                const float* __restrict__ bq,
                                                const float* __restrict__ bv,
                                                float* Q, float* K, float* V,
                                                int b0, int nTok,
                                                const int* __restrict__ flag) {
    if (!((*flag) & 2)) return;
    spin_fma(24000);    // +~40us marker: K-region fired
    repair_region(hs, Wtf, bq, bv, Q, K, V, b0, nTok, 1);
}
__global__ __launch_bounds__(256) void repair_v(const float* __restrict__ hs,
                                                const float* __restrict__ Wtf,
                                                const float* __restrict__ bq,
                                                const float* __restrict__ bv,
                                                float* Q, float* K, float* V,
                                                int b0, int nTok,
                                                const int* __restrict__ flag) {
    if (!((*flag) & 4)) return;
    spin_fma(48000);    // +~80us marker: V-region fired
    repair_region(hs, Wtf, bq, bv, Q, K, V, b0, nTok, 2);
}

// -------- cls attention (unchanged)
__global__ __launch_bounds__(256) void cls_attn(const float* __restrict__ Q,
                                                const float* __restrict__ K,
                                                const float* __restrict__ V,
                                                const float* __restrict__ rel,
                                                const int* __restrict__ rpi,
                                                float* __restrict__ out, int b0) {
    int bh = blockIdx.x;
    int bl = bh / 12, h = bh - bl * 12;
    __shared__ float p[S_TOT];
    __shared__ float4 qs4[16];
    __shared__ float red[256];
    __shared__ float wred[8];
    int tid = threadIdx.x, lane = tid & 63, w = tid >> 6;
    size_t base = (size_t)bh * S_TOT * 64;
    const float* Qb = Q + base;
    const float* Kb = K + base;
    const float* Vb = V + base;
    if (tid < 64) ((float*)qs4)[tid] = Qb[tid];
    __syncthreads();

    float lmx = -1e30f;
    for (int j = tid; j < S_TOT; j += 256) {
        const float4* kr = (const float4*)(Kb + j * 64);
        float a = 0.f;
#pragma unroll
        for (int d4 = 0; d4 < 16; d4++) {
            float4 kv = kr[d4];
            float4 qv = qs4[d4];
            a = fmaf(qv.x, kv.x, a); a = fmaf(qv.y, kv.y, a);
            a = fmaf(qv.z, kv.z, a); a = fmaf(qv.w, kv.w, a);
        }
        a = a * 0.125f + rel[rpi[j] * 12 + h];
        p[j] = a;
        lmx = fmaxf(lmx, a);
    }
#pragma unroll
    for (int off = 32; off > 0; off >>= 1) lmx = fmaxf(lmx, __shfl_xor(lmx, off));
    if (lane == 0) wred[w] = lmx;
    __syncthreads();
    float mx = fmaxf(fmaxf(wred[0], wred[1]), fmaxf(wred[2], wred[3]));
    float lsum = 0.f;
    for (int j = tid; j < S_TOT; j += 256) {
        float e = __expf(p[j] - mx);
        p[j] = e;
        lsum += e;
    }
#pragma unroll
    for (int off = 32; off > 0; off >>= 1) lsum += __shfl_xor(lsum, off);
    if (lane == 0) wred[4 + w] = lsum;
    __syncthreads();
    float inv = 1.0f / (wred[4] + wred[5] + wred[6] + wred[7]);
    float acc = 0.f;
    for (int j = w; j < S_TOT; j += 4) acc = fmaf(p[j], Vb[j * 64 + lane], acc);
    red[w * 64 + lane] = acc;
    __syncthreads();
    if (w == 0) {
        float o = (red[lane] + red[64 + lane] + red[128 + lane] + red[192 + lane]) * inv;
        out[(size_t)(b0 + bl) * S_TOT * 768 + h * 64 + lane] = o;
    }
}

// -------- block-sparse local attention — flash-style online softmax (unchanged)
__global__ __launch_bounds__(256, 4) void loc_attn(const float* __restrict__ Q,
                                                   const float* __restrict__ K,
                                                   const float* __restrict__ V,
                                                   const float* __restrict__ rel,
                                                   const int* __restrict__ rpi,
                                                   const int* __restrict__ rand_idx,
                                                   float* __restrict__ out, int b0) {
    int m = blockIdx.x;
    int h = blockIdx.y;
    int bl = blockIdx.z;
    __shared__ float Qlds[52][64];      // rows 49..51 zero-filled
    __shared__ float Plds[4][13][64];   // per-wave P chunk transpose buffer
    __shared__ int   tok[320];          // 295 real + padding (token 0)
    int tid = threadIdx.x, lane = tid & 63, w = tid >> 6;

    size_t base = (size_t)((bl * 12 + h) * S_TOT) * 64;
    const float* Qb = Q + base;
    const float* Kb = K + base;
    const float* Vb = V + base;

    // stage token table (295 entries, pad to 320 with token 0)
    for (int jj = tid; jj < 320; jj += 256) {
        int t = 0;
        if (jj >= 1 && jj < 295) {
            int j1 = jj - 1;
            int n = j1 / 49;
            int q = j1 - n * 49;
            int a;
            if (n == 0)      a = (m + 31) & 31;
            else if (n == 1) a = m;
            else if (n == 2) a = (m + 1) & 31;
            else             a = rand_idx[m * 3 + (n - 3)];
            t = 1 + a * 49 + q;
        }
        tok[jj] = t;
    }
    // stage Q tile (49 rows + 3 zero rows), coalesced
    for (int idx = tid; idx < 52 * 64; idx += 256) {
        int r = idx >> 6, c = idx & 63;
        float qv = 0.f;
        if (r < 49) qv = Qb[(size_t)(1 + m * 49 + r) * 64 + c];
        ((float*)Qlds)[idx] = qv;
    }
    __syncthreads();

    float fm[13], fl[13], facc[13];
#pragma unroll
    for (int r = 0; r < 13; r++) { fm[r] = -1e30f; fl[r] = 0.f; facc[r] = 0.f; }

    for (int jc = 0; jc < 5; jc++) {
        int j = jc * 64 + lane;
        int tj = tok[j];
        const float* kp = Kb + (size_t)tj * 64;

        // ---- QK^T for this 64-key chunk: s[r] = Q[i]·K[tj]
        float s[13];
#pragma unroll
        for (int r = 0; r < 13; r++) s[r] = 0.f;
#pragma unroll 4
        for (int d4 = 0; d4 < 16; d4++) {
            float4 kv = *(const float4*)(kp + d4 * 4);
#pragma unroll
            for (int r = 0; r < 13; r++) {
                float4 qv = *(const float4*)&Qlds[w + 4 * r][d4 * 4];   // broadcast
                s[r] = fmaf(qv.x, kv.x, s[r]);
                s[r] = fmaf(qv.y, kv.y, s[r]);
                s[r] = fmaf(qv.z, kv.z, s[r]);
                s[r] = fmaf(qv.w, kv.w, s[r]);
            }
        }

        // ---- bias + online softmax (per-row butterflies), write P chunk
        bool jv = j < 295;
#pragma unroll
        for (int r = 0; r < 13; r++) {
            int i = w + 4 * r;
            int qr = 1 + m * 49 + i;
            if (qr > S_TOT - 1) qr = S_TOT - 1;   // clamp for pad rows 49..51
            float sv = jv ? fmaf(s[r], 0.125f, rel[rpi[(size_t)qr * S_TOT + tj] * 12 + h])
                          : -1e30f;
            float mx = sv;
#pragma unroll
            for (int off = 32; off > 0; off >>= 1) mx = fmaxf(mx, __shfl_xor(mx, off));
            float mnew = fmaxf(fm[r], mx);
            float p = __expf(sv - mnew);
            float alpha = __expf(fm[r] - mnew);
            fm[r] = mnew;
            float ps = p;
#pragma unroll
            for (int off = 32; off > 0; off >>= 1) ps += __shfl_xor(ps, off);
            fl[r] = fmaf(fl[r], alpha, ps);
            facc[r] *= alpha;
            Plds[w][r][lane] = p;
        }

        // ---- PV for this chunk: 4 keys per step, P via b128 broadcast
#pragma unroll 4
        for (int jg = 0; jg < 16; jg++) {
            int jb = jc * 64 + jg * 4;
            int t0 = tok[jb + 0], t1 = tok[jb + 1], t2 = tok[jb + 2], t3 = tok[jb + 3];
            float v0 = Vb[(size_t)t0 * 64 + lane];
            float v1 = Vb[(size_t)t1 * 64 + lane];
            float v2 = Vb[(size_t)t2 * 64 + lane];
            float v3 = Vb[(size_t)t3 * 64 + lane];
#pragma unroll
            for (int r = 0; r < 13; r++) {
                float4 p4 = *(const float4*)&Plds[w][r][jg * 4];        // broadcast
                facc[r] = fmaf(p4.x, v0, facc[r]);
                facc[r] = fmaf(p4.y, v1, facc[r]);
                facc[r] = fmaf(p4.z, v2, facc[r]);
                facc[r] = fmaf(p4.w, v3, facc[r]);
            }
        }
    }

    // ---- epilogue: normalize and store valid rows
    int nrows = (w == 0) ? 13 : 12;
    for (int r = 0; r < nrows; r++) {
        int i = w + 4 * r;
        int st = 1 + m * 49 + i;
        out[((size_t)(b0 + bl) * S_TOT + st) * 768 + h * 64 + lane] = facc[r] / fl[r];
    }
}

extern "C" void kernel_launch(void* const* d_in, const int* in_sizes, int n_in,
                              void* d_out, int out_size, void* d_ws, size_t ws_size,
                              hipStream_t stream) {
    (void)in_sizes; (void)n_in; (void)out_size;
    const float* hs  = (const float*)d_in[0];
    const float* Wq  = (const float*)d_in[1];
    const float* bq  = (const float*)d_in[2];
    const float* Wk  = (const float*)d_in[3];
    const float* Wv  = (const float*)d_in[4];
    const float* bv  = (const float*)d_in[5];
    const float* rel = (const float*)d_in[6];
    const int*   rpi = (const int*)d_in[7];
    const int*   rnd = (const int*)d_in[8];
    float* out = (float*)d_out;
    char* ws = (char*)d_ws;

    // ws layout: flag | Xhi bf16 | Xlo bf16 | Whi bf16 | Wlo bf16 | Wtf f32 | QKV f32
    constexpr size_t FLAG_OFF = 0;
    constexpr size_t XHI_OFF  = 64;
    constexpr size_t XLO_OFF  = XHI_OFF + (size_t)NX * 2;            // +19,275,264
    constexpr size_t WHI_OFF  = XLO_OFF + (size_t)NX * 2;
    constexpr size_t WLO_OFF  = WHI_OFF + (size_t)NCOL * 768 * 2;    // +3,538,944
    constexpr size_t WTF_OFF  = WLO_OFF + (size_t)NCOL * 768 * 2;    // +3,538,944
    constexpr size_t QKV_OFF  = WTF_OFF + (size_t)NCOL * 768 * 4;    // +7,077,888
    constexpr size_t PBUF     = (size_t)12 * S_TOT * 64 * 4;         //  4,819,968

    int*   flag = (int*)(ws + FLAG_OFF);
    u16*   Xhi  = (u16*)(ws + XHI_OFF);
    u16*   Xlo  = (u16*)(ws + XLO_OFF);
    u16*   Whi  = (u16*)(ws + WHI_OFF);
    u16*   Wlo  = (u16*)(ws + WLO_OFF);
    float* Wtf  = (float*)(ws + WTF_OFF);

    int C = 1;
    if (ws_size > QKV_OFF + 3 * PBUF) {
        size_t c = (ws_size - QKV_OFF) / (3 * PBUF);
        C = (c >= NBATCH) ? NBATCH : (int)c;
        if (C < 1) C = 1;
    }
    float* Q = (float*)(ws + QKV_OFF);
    float* K = (float*)(ws + QKV_OFF + (size_t)C * PBUF);
    float* V = (float*)(ws + QKV_OFF + (size_t)C * PBUF * 2);

    init_flag<<<dim3(1), dim3(1), 0, stream>>>(flag);
    conv_x<<<dim3((NX / 8 + 255) / 256), dim3(256), 0, stream>>>(hs, Xhi, Xlo);
    conv_w2<<<dim3(72, 24), dim3(256), 0, stream>>>(Wq, Wk, Wv, Wtf, Whi, Wlo);

    for (int b0 = 0; b0 < NBATCH; b0 += C) {
        int cb = (NBATCH - b0 < C) ? (NBATCH - b0) : C;
        int nTok = cb * S_TOT;
        gemm_qkv<<<dim3((nTok + 127) / 128, NCOL / 128), dim3(256), 0, stream>>>(
            Xhi, Xlo, Whi, Wlo, bq, bv, Q, K, V, b0, nTok);
        check_gemm<<<dim3(6, NCOL / 64), dim3(256), 0, stream>>>(
            hs, Wtf, bq, bv, Q, K, V, b0, nTok, flag);
        dim3 rg((nTok + 63) / 64, 12);
        repair_q<<<rg, dim3(256), 0, stream>>>(hs, Wtf, bq, bv, Q, K, V, b0, nTok, flag);
        repair_k<<<rg, dim3(256), 0, stream>>>(hs, Wtf, bq, bv, Q, K, V, b0, nTok, flag);
        repair_v<<<rg, dim3(256), 0, stream>>>(hs, Wtf, bq, bv, Q, K, V, b0, nTok, flag);
        cls_attn<<<dim3(12 * cb), dim3(256), 0, stream>>>(Q, K, V, rel, rpi, out, b0);
        loc_attn<<<dim3(32, 12, cb), dim3(256), 0, stream>>>(Q, K, V, rel, rpi, rnd, out, b0);
    }
}

// Round 5
// 1245.602 us; speedup vs baseline: 2.0731x; 2.0731x over previous
//
#include <hip/hip_runtime.h>

// BeitSelfAttention — clean f32 pipeline (this round).
// The MFMA split-bf16 path + check/repair apparatus is DELETED: diagnosis
// rounds proved its output is structurally wrong everywhere (all Q/K/V
// regions fail a 2e-3 check even with triple-split ~1e-5 numerics), so the
// f32 repair was silently recomputing 100% of QKV every launch. This round
// replaces that ~1080us path (conv_x + conv_w2 + gemm_qkv + check + 3x
// repair) with ONE optimized f32 GEMM:
//   gemm_f32: 128x128 tile, 256 thr, 8x8 micro (2 FLOP/LDS-byte, exactly
//   balanced vs 128 B/cyc LDS roofline), reads X and W directly (no
//   pre-transpose, no bf16 conversion), bank-conflict-free-by-design
//   (A-reads broadcast; B-reads 2-way via split cols tc*4 / 64+tc*4).
// cls_attn / loc_attn (flash-style) verbatim from previous rounds.
// Shapes: B=8 S=1569 D=768 NH=12 DH=64 NCLS=1 BS=49 M=32 NKV=6

#define S_TOT   1569
#define NBATCH  8

// -------- gemm_f32: QKV = X(nTok x 768) @ [Wq|Wk|Wv](768 x 2304) + bias
// grid: ((nTok+127)/128, 18), block 256. Each 128-col block lies in exactly
// one of Wq/Wk/Wv (768/128=6). Output scattered to per-head [B*12][S][64].
__global__ __launch_bounds__(256) void gemm_f32(const float* __restrict__ hs,
                                                const float* __restrict__ Wq,
                                                const float* __restrict__ Wk,
                                                const float* __restrict__ Wv,
                                                const float* __restrict__ bq,
                                                const float* __restrict__ bv,
                                                float* __restrict__ Q,
                                                float* __restrict__ K,
                                                float* __restrict__ V,
                                                int b0, int nTok) {
    __shared__ float As[128][20];   // [t][k]: 16 k + 4 pad (80B row, 16B-aligned)
    __shared__ float Bs[16][136];   // [k][n]: 128 n + 8 pad (544B row, 16B-aligned)
    int tid = threadIdx.x;
    int t0 = blockIdx.x * 128;
    int n0 = blockIdx.y * 128;
    int which = n0 / 768;
    int ng0 = n0 - which * 768;
    const float* W = (which == 0) ? Wq : (which == 1 ? Wk : Wv);
    const float* Xb = hs + (size_t)b0 * S_TOT * 768;

    int tr = tid >> 4;              // 0..15: rows tr*8 .. tr*8+7
    int tc = tid & 15;              // cols tc*4..+4 and 64+tc*4..+4 (2-way-free B reads)

    // staging assignments
    int sat = tid >> 2;             // 0..63 (+0 / +64 halves)
    int sak = (tid & 3) * 4;        // k-offset 0,4,8,12
    int sbk = tid >> 4;             // 0..15
    int sbn = (tid & 15) * 8;       // 0..120

    float acc[8][8];
#pragma unroll
    for (int i = 0; i < 8; i++)
#pragma unroll
        for (int j = 0; j < 8; j++) acc[i][j] = 0.f;

    for (int k0 = 0; k0 < 768; k0 += 16) {
        // ---- stage A: X[t0..t0+128][k0..k0+16]
#pragma unroll
        for (int hh = 0; hh < 2; hh++) {
            int t = t0 + sat + hh * 64;
            float4 xv = make_float4(0.f, 0.f, 0.f, 0.f);
            if (t < nTok)
                xv = *(const float4*)(Xb + (size_t)t * 768 + k0 + sak);
            *(float4*)&As[sat + hh * 64][sak] = xv;
        }
        // ---- stage B: W[k0..k0+16][ng0..ng0+128] (rows contiguous along n)
        {
            const float* wr_ = W + (size_t)(k0 + sbk) * 768 + ng0 + sbn;
            *(float4*)&Bs[sbk][sbn]     = *(const float4*)(wr_);
            *(float4*)&Bs[sbk][sbn + 4] = *(const float4*)(wr_ + 4);
        }
        __syncthreads();

#pragma unroll
        for (int kq = 0; kq < 4; kq++) {
            float4 xa[8];
#pragma unroll
            for (int i = 0; i < 8; i++)
                xa[i] = *(const float4*)&As[tr * 8 + i][kq * 4];
#pragma unroll
            for (int kk = 0; kk < 4; kk++) {
                int k = kq * 4 + kk;
                float4 w0 = *(const float4*)&Bs[k][tc * 4];
                float4 w1 = *(const float4*)&Bs[k][64 + tc * 4];
#pragma unroll
                for (int i = 0; i < 8; i++) {
                    float a = (kk == 0) ? xa[i].x : (kk == 1) ? xa[i].y
                            : (kk == 2) ? xa[i].z : xa[i].w;
                    acc[i][0] = fmaf(a, w0.x, acc[i][0]);
                    acc[i][1] = fmaf(a, w0.y, acc[i][1]);
                    acc[i][2] = fmaf(a, w0.z, acc[i][2]);
                    acc[i][3] = fmaf(a, w0.w, acc[i][3]);
                    acc[i][4] = fmaf(a, w1.x, acc[i][4]);
                    acc[i][5] = fmaf(a, w1.y, acc[i][5]);
                    acc[i][6] = fmaf(a, w1.z, acc[i][6]);
                    acc[i][7] = fmaf(a, w1.w, acc[i][7]);
                }
            }
        }
        __syncthreads();
    }

    // ---- epilogue: bias + scatter to per-head layout; float4 stores
    float* dst = (which == 0) ? Q : (which == 1 ? K : V);
    const float* bias = (which == 0) ? bq : (which == 2 ? bv : nullptr);
#pragma unroll
    for (int hh = 0; hh < 2; hh++) {
        int nn = ng0 + hh * 64 + tc * 4;        // 0..767, multiple of 4
        int h = nn >> 6, d = nn & 63;
        float4 bv4 = make_float4(0.f, 0.f, 0.f, 0.f);
        if (bias) bv4 = *(const float4*)(bias + nn);
#pragma unroll
        for (int i = 0; i < 8; i++) {
            int t = t0 + tr * 8 + i;
            if (t >= nTok) continue;
            int bl = t / S_TOT;
            int s = t - bl * S_TOT;
            float4 o;
            o.x = acc[i][hh * 4 + 0] + bv4.x;
            o.y = acc[i][hh * 4 + 1] + bv4.y;
            o.z = acc[i][hh * 4 + 2] + bv4.z;
            o.w = acc[i][hh * 4 + 3] + bv4.w;
            *(float4*)(dst + ((size_t)(bl * 12 + h) * S_TOT + s) * 64 + d) = o;
        }
    }
}

// -------- cls attention (unchanged)
__global__ __launch_bounds__(256) void cls_attn(const float* __restrict__ Q,
                                                const float* __restrict__ K,
                                                const float* __restrict__ V,
                                                const float* __restrict__ rel,
                                                const int* __restrict__ rpi,
                                                float* __restrict__ out, int b0) {
    int bh = blockIdx.x;
    int bl = bh / 12, h = bh - bl * 12;
    __shared__ float p[S_TOT];
    __shared__ float4 qs4[16];
    __shared__ float red[256];
    __shared__ float wred[8];
    int tid = threadIdx.x, lane = tid & 63, w = tid >> 6;
    size_t base = (size_t)bh * S_TOT * 64;
    const float* Qb = Q + base;
    const float* Kb = K + base;
    const float* Vb = V + base;
    if (tid < 64) ((float*)qs4)[tid] = Qb[tid];
    __syncthreads();

    float lmx = -1e30f;
    for (int j = tid; j < S_TOT; j += 256) {
        const float4* kr = (const float4*)(Kb + j * 64);
        float a = 0.f;
#pragma unroll
        for (int d4 = 0; d4 < 16; d4++) {
            float4 kv = kr[d4];
            float4 qv = qs4[d4];
            a = fmaf(qv.x, kv.x, a); a = fmaf(qv.y, kv.y, a);
            a = fmaf(qv.z, kv.z, a); a = fmaf(qv.w, kv.w, a);
        }
        a = a * 0.125f + rel[rpi[j] * 12 + h];
        p[j] = a;
        lmx = fmaxf(lmx, a);
    }
#pragma unroll
    for (int off = 32; off > 0; off >>= 1) lmx = fmaxf(lmx, __shfl_xor(lmx, off));
    if (lane == 0) wred[w] = lmx;
    __syncthreads();
    float mx = fmaxf(fmaxf(wred[0], wred[1]), fmaxf(wred[2], wred[3]));
    float lsum = 0.f;
    for (int j = tid; j < S_TOT; j += 256) {
        float e = __expf(p[j] - mx);
        p[j] = e;
        lsum += e;
    }
#pragma unroll
    for (int off = 32; off > 0; off >>= 1) lsum += __shfl_xor(lsum, off);
    if (lane == 0) wred[4 + w] = lsum;
    __syncthreads();
    float inv = 1.0f / (wred[4] + wred[5] + wred[6] + wred[7]);
    float acc = 0.f;
    for (int j = w; j < S_TOT; j += 4) acc = fmaf(p[j], Vb[j * 64 + lane], acc);
    red[w * 64 + lane] = acc;
    __syncthreads();
    if (w == 0) {
        float o = (red[lane] + red[64 + lane] + red[128 + lane] + red[192 + lane]) * inv;
        out[(size_t)(b0 + bl) * S_TOT * 768 + h * 64 + lane] = o;
    }
}

// -------- block-sparse local attention — flash-style online softmax (unchanged)
__global__ __launch_bounds__(256, 4) void loc_attn(const float* __restrict__ Q,
                                                   const float* __restrict__ K,
                                                   const float* __restrict__ V,
                                                   const float* __restrict__ rel,
                                                   const int* __restrict__ rpi,
                                                   const int* __restrict__ rand_idx,
                                                   float* __restrict__ out, int b0) {
    int m = blockIdx.x;
    int h = blockIdx.y;
    int bl = blockIdx.z;
    __shared__ float Qlds[52][64];      // rows 49..51 zero-filled
    __shared__ float Plds[4][13][64];   // per-wave P chunk transpose buffer
    __shared__ int   tok[320];          // 295 real + padding (token 0)
    int tid = threadIdx.x, lane = tid & 63, w = tid >> 6;

    size_t base = (size_t)((bl * 12 + h) * S_TOT) * 64;
    const float* Qb = Q + base;
    const float* Kb = K + base;
    const float* Vb = V + base;

    // stage token table (295 entries, pad to 320 with token 0)
    for (int jj = tid; jj < 320; jj += 256) {
        int t = 0;
        if (jj >= 1 && jj < 295) {
            int j1 = jj - 1;
            int n = j1 / 49;
            int q = j1 - n * 49;
            int a;
            if (n == 0)      a = (m + 31) & 31;
            else if (n == 1) a = m;
            else if (n == 2) a = (m + 1) & 31;
            else             a = rand_idx[m * 3 + (n - 3)];
            t = 1 + a * 49 + q;
        }
        tok[jj] = t;
    }
    // stage Q tile (49 rows + 3 zero rows), coalesced
    for (int idx = tid; idx < 52 * 64; idx += 256) {
        int r = idx >> 6, c = idx & 63;
        float qv = 0.f;
        if (r < 49) qv = Qb[(size_t)(1 + m * 49 + r) * 64 + c];
        ((float*)Qlds)[idx] = qv;
    }
    __syncthreads();

    float fm[13], fl[13], facc[13];
#pragma unroll
    for (int r = 0; r < 13; r++) { fm[r] = -1e30f; fl[r] = 0.f; facc[r] = 0.f; }

    for (int jc = 0; jc < 5; jc++) {
        int j = jc * 64 + lane;
        int tj = tok[j];
        const float* kp = Kb + (size_t)tj * 64;

        // ---- QK^T for this 64-key chunk: s[r] = Q[i]·K[tj]
        float s[13];
#pragma unroll
        for (int r = 0; r < 13; r++) s[r] = 0.f;
#pragma unroll 4
        for (int d4 = 0; d4 < 16; d4++) {
            float4 kv = *(const float4*)(kp + d4 * 4);
#pragma unroll
            for (int r = 0; r < 13; r++) {
                float4 qv = *(const float4*)&Qlds[w + 4 * r][d4 * 4];   // broadcast
                s[r] = fmaf(qv.x, kv.x, s[r]);
                s[r] = fmaf(qv.y, kv.y, s[r]);
                s[r] = fmaf(qv.z, kv.z, s[r]);
                s[r] = fmaf(qv.w, kv.w, s[r]);
            }
        }

        // ---- bias + online softmax (per-row butterflies), write P chunk
        bool jv = j < 295;
#pragma unroll
        for (int r = 0; r < 13; r++) {
            int i = w + 4 * r;
            int qr = 1 + m * 49 + i;
            if (qr > S_TOT - 1) qr = S_TOT - 1;   // clamp for pad rows 49..51
            float sv = jv ? fmaf(s[r], 0.125f, rel[rpi[(size_t)qr * S_TOT + tj] * 12 + h])
                          : -1e30f;
            float mx = sv;
#pragma unroll
            for (int off = 32; off > 0; off >>= 1) mx = fmaxf(mx, __shfl_xor(mx, off));
            float mnew = fmaxf(fm[r], mx);
            float p = __expf(sv - mnew);
            float alpha = __expf(fm[r] - mnew);
            fm[r] = mnew;
            float ps = p;
#pragma unroll
            for (int off = 32; off > 0; off >>= 1) ps += __shfl_xor(ps, off);
            fl[r] = fmaf(fl[r], alpha, ps);
            facc[r] *= alpha;
            Plds[w][r][lane] = p;
        }

        // ---- PV for this chunk: 4 keys per step, P via b128 broadcast
#pragma unroll 4
        for (int jg = 0; jg < 16; jg++) {
            int jb = jc * 64 + jg * 4;
            int t0 = tok[jb + 0], t1 = tok[jb + 1], t2 = tok[jb + 2], t3 = tok[jb + 3];
            float v0 = Vb[(size_t)t0 * 64 + lane];
            float v1 = Vb[(size_t)t1 * 64 + lane];
            float v2 = Vb[(size_t)t2 * 64 + lane];
            float v3 = Vb[(size_t)t3 * 64 + lane];
#pragma unroll
            for (int r = 0; r < 13; r++) {
                float4 p4 = *(const float4*)&Plds[w][r][jg * 4];        // broadcast
                facc[r] = fmaf(p4.x, v0, facc[r]);
                facc[r] = fmaf(p4.y, v1, facc[r]);
                facc[r] = fmaf(p4.z, v2, facc[r]);
                facc[r] = fmaf(p4.w, v3, facc[r]);
            }
        }
    }

    // ---- epilogue: normalize and store valid rows
    int nrows = (w == 0) ? 13 : 12;
    for (int r = 0; r < nrows; r++) {
        int i = w + 4 * r;
        int st = 1 + m * 49 + i;
        out[((size_t)(b0 + bl) * S_TOT + st) * 768 + h * 64 + lane] = facc[r] / fl[r];
    }
}

extern "C" void kernel_launch(void* const* d_in, const int* in_sizes, int n_in,
                              void* d_out, int out_size, void* d_ws, size_t ws_size,
                              hipStream_t stream) {
    (void)in_sizes; (void)n_in; (void)out_size;
    const float* hs  = (const float*)d_in[0];
    const float* Wq  = (const float*)d_in[1];
    const float* bq  = (const float*)d_in[2];
    const float* Wk  = (const float*)d_in[3];
    const float* Wv  = (const float*)d_in[4];
    const float* bv  = (const float*)d_in[5];
    const float* rel = (const float*)d_in[6];
    const int*   rpi = (const int*)d_in[7];
    const int*   rnd = (const int*)d_in[8];
    float* out = (float*)d_out;
    char* ws = (char*)d_ws;

    // ws layout: Q | K | V  (each C * PBUF bytes)
    constexpr size_t PBUF = (size_t)12 * S_TOT * 64 * 4;     // 4,819,968 per batch

    int C = 1;
    if (ws_size >= 3 * PBUF) {
        size_t c = ws_size / (3 * PBUF);
        C = (c >= NBATCH) ? NBATCH : (int)c;
        if (C < 1) C = 1;
    }
    float* Q = (float*)(ws);
    float* K = (float*)(ws + (size_t)C * PBUF);
    float* V = (float*)(ws + (size_t)C * PBUF * 2);

    for (int b0 = 0; b0 < NBATCH; b0 += C) {
        int cb = (NBATCH - b0 < C) ? (NBATCH - b0) : C;
        int nTok = cb * S_TOT;
        gemm_f32<<<dim3((nTok + 127) / 128, 18), dim3(256), 0, stream>>>(
            hs, Wq, Wk, Wv, bq, bv, Q, K, V, b0, nTok);
        cls_attn<<<dim3(12 * cb), dim3(256), 0, stream>>>(Q, K, V, rel, rpi, out, b0);
        loc_attn<<<dim3(32, 12, cb), dim3(256), 0, stream>>>(Q, K, V, rel, rpi, rnd, out, b0);
    }
}

// Round 6
// 1201.682 us; speedup vs baseline: 2.1489x; 1.0365x over previous
//
#include <hip/hip_runtime.h>

// BeitSelfAttention — f32 pipeline, loc_attn memory-side round.
// This round (loc_attn only):
//  (1) XCD-aware block swizzle: 1-D grid, slot=(d%8)*(total/8)+d/8 keeps all
//      32 m-blocks of one (bl,h) on one XCD -> K/V slab (800KB) stays L2-hot.
//      Was: 8 XCDs each fetching its own copy (FETCH 517MB vs 77MB unique).
//  (2) rpi gather ELIMINATED: rel_pos_index is pure structure. For qr,tj>=1:
//      idx = (dz+7)*729+(dy+13)*27+(dx+13), coords p=z*196+y*14+x (8,14,14);
//      idx[qr][0]=10936. Hoisted: cq[r] per row, cj per (chunk,lane);
//      bidx = cq[r]-cj+5467. Removes 16640 scattered 4B loads/block + the
//      dependent-gather latency chain. rel (525KB, L2-resident) still gathered.
// gemm_f32 / cls_attn verbatim from round 5.
// Shapes: B=8 S=1569 D=768 NH=12 DH=64 NCLS=1 BS=49 M=32 NKV=6

#define S_TOT   1569
#define NBATCH  8

// -------- gemm_f32: QKV = X(nTok x 768) @ [Wq|Wk|Wv](768 x 2304) + bias
__global__ __launch_bounds__(256) void gemm_f32(const float* __restrict__ hs,
                                                const float* __restrict__ Wq,
                                                const float* __restrict__ Wk,
                                                const float* __restrict__ Wv,
                                                const float* __restrict__ bq,
                                                const float* __restrict__ bv,
                                                float* __restrict__ Q,
                                                float* __restrict__ K,
                                                float* __restrict__ V,
                                                int b0, int nTok) {
    __shared__ float As[128][20];   // [t][k]: 16 k + 4 pad
    __shared__ float Bs[16][136];   // [k][n]: 128 n + 8 pad
    int tid = threadIdx.x;
    int t0 = blockIdx.x * 128;
    int n0 = blockIdx.y * 128;
    int which = n0 / 768;
    int ng0 = n0 - which * 768;
    const float* W = (which == 0) ? Wq : (which == 1 ? Wk : Wv);
    const float* Xb = hs + (size_t)b0 * S_TOT * 768;

    int tr = tid >> 4;              // 0..15: rows tr*8 .. tr*8+7
    int tc = tid & 15;              // cols tc*4..+4 and 64+tc*4..+4

    int sat = tid >> 2;             // 0..63 (+0 / +64 halves)
    int sak = (tid & 3) * 4;        // k-offset 0,4,8,12
    int sbk = tid >> 4;             // 0..15
    int sbn = (tid & 15) * 8;       // 0..120

    float acc[8][8];
#pragma unroll
    for (int i = 0; i < 8; i++)
#pragma unroll
        for (int j = 0; j < 8; j++) acc[i][j] = 0.f;

    for (int k0 = 0; k0 < 768; k0 += 16) {
#pragma unroll
        for (int hh = 0; hh < 2; hh++) {
            int t = t0 + sat + hh * 64;
            float4 xv = make_float4(0.f, 0.f, 0.f, 0.f);
            if (t < nTok)
                xv = *(const float4*)(Xb + (size_t)t * 768 + k0 + sak);
            *(float4*)&As[sat + hh * 64][sak] = xv;
        }
        {
            const float* wr_ = W + (size_t)(k0 + sbk) * 768 + ng0 + sbn;
            *(float4*)&Bs[sbk][sbn]     = *(const float4*)(wr_);
            *(float4*)&Bs[sbk][sbn + 4] = *(const float4*)(wr_ + 4);
        }
        __syncthreads();

#pragma unroll
        for (int kq = 0; kq < 4; kq++) {
            float4 xa[8];
#pragma unroll
            for (int i = 0; i < 8; i++)
                xa[i] = *(const float4*)&As[tr * 8 + i][kq * 4];
#pragma unroll
            for (int kk = 0; kk < 4; kk++) {
                int k = kq * 4 + kk;
                float4 w0 = *(const float4*)&Bs[k][tc * 4];
                float4 w1 = *(const float4*)&Bs[k][64 + tc * 4];
#pragma unroll
                for (int i = 0; i < 8; i++) {
                    float a = (kk == 0) ? xa[i].x : (kk == 1) ? xa[i].y
                            : (kk == 2) ? xa[i].z : xa[i].w;
                    acc[i][0] = fmaf(a, w0.x, acc[i][0]);
                    acc[i][1] = fmaf(a, w0.y, acc[i][1]);
                    acc[i][2] = fmaf(a, w0.z, acc[i][2]);
                    acc[i][3] = fmaf(a, w0.w, acc[i][3]);
                    acc[i][4] = fmaf(a, w1.x, acc[i][4]);
                    acc[i][5] = fmaf(a, w1.y, acc[i][5]);
                    acc[i][6] = fmaf(a, w1.z, acc[i][6]);
                    acc[i][7] = fmaf(a, w1.w, acc[i][7]);
                }
            }
        }
        __syncthreads();
    }

    float* dst = (which == 0) ? Q : (which == 1 ? K : V);
    const float* bias = (which == 0) ? bq : (which == 2 ? bv : nullptr);
#pragma unroll
    for (int hh = 0; hh < 2; hh++) {
        int nn = ng0 + hh * 64 + tc * 4;        // 0..767, multiple of 4
        int h = nn >> 6, d = nn & 63;
        float4 bv4 = make_float4(0.f, 0.f, 0.f, 0.f);
        if (bias) bv4 = *(const float4*)(bias + nn);
#pragma unroll
        for (int i = 0; i < 8; i++) {
            int t = t0 + tr * 8 + i;
            if (t >= nTok) continue;
            int bl = t / S_TOT;
            int s = t - bl * S_TOT;
            float4 o;
            o.x = acc[i][hh * 4 + 0] + bv4.x;
            o.y = acc[i][hh * 4 + 1] + bv4.y;
            o.z = acc[i][hh * 4 + 2] + bv4.z;
            o.w = acc[i][hh * 4 + 3] + bv4.w;
            *(float4*)(dst + ((size_t)(bl * 12 + h) * S_TOT + s) * 64 + d) = o;
        }
    }
}

// -------- cls attention (unchanged)
__global__ __launch_bounds__(256) void cls_attn(const float* __restrict__ Q,
                                                const float* __restrict__ K,
                                                const float* __restrict__ V,
                                                const float* __restrict__ rel,
                                                const int* __restrict__ rpi,
                                                float* __restrict__ out, int b0) {
    int bh = blockIdx.x;
    int bl = bh / 12, h = bh - bl * 12;
    __shared__ float p[S_TOT];
    __shared__ float4 qs4[16];
    __shared__ float red[256];
    __shared__ float wred[8];
    int tid = threadIdx.x, lane = tid & 63, w = tid >> 6;
    size_t base = (size_t)bh * S_TOT * 64;
    const float* Qb = Q + base;
    const float* Kb = K + base;
    const float* Vb = V + base;
    if (tid < 64) ((float*)qs4)[tid] = Qb[tid];
    __syncthreads();

    float lmx = -1e30f;
    for (int j = tid; j < S_TOT; j += 256) {
        const float4* kr = (const float4*)(Kb + j * 64);
        float a = 0.f;
#pragma unroll
        for (int d4 = 0; d4 < 16; d4++) {
            float4 kv = kr[d4];
            float4 qv = qs4[d4];
            a = fmaf(qv.x, kv.x, a); a = fmaf(qv.y, kv.y, a);
            a = fmaf(qv.z, kv.z, a); a = fmaf(qv.w, kv.w, a);
        }
        a = a * 0.125f + rel[rpi[j] * 12 + h];
        p[j] = a;
        lmx = fmaxf(lmx, a);
    }
#pragma unroll
    for (int off = 32; off > 0; off >>= 1) lmx = fmaxf(lmx, __shfl_xor(lmx, off));
    if (lane == 0) wred[w] = lmx;
    __syncthreads();
    float mx = fmaxf(fmaxf(wred[0], wred[1]), fmaxf(wred[2], wred[3]));
    float lsum = 0.f;
    for (int j = tid; j < S_TOT; j += 256) {
        float e = __expf(p[j] - mx);
        p[j] = e;
        lsum += e;
    }
#pragma unroll
    for (int off = 32; off > 0; off >>= 1) lsum += __shfl_xor(lsum, off);
    if (lane == 0) wred[4 + w] = lsum;
    __syncthreads();
    float inv = 1.0f / (wred[4] + wred[5] + wred[6] + wred[7]);
    float acc = 0.f;
    for (int j = w; j < S_TOT; j += 4) acc = fmaf(p[j], Vb[j * 64 + lane], acc);
    red[w * 64 + lane] = acc;
    __syncthreads();
    if (w == 0) {
        float o = (red[lane] + red[64 + lane] + red[128 + lane] + red[192 + lane]) * inv;
        out[(size_t)(b0 + bl) * S_TOT * 768 + h * 64 + lane] = o;
    }
}

// -------- block-sparse local attention — flash-style, XCD-swizzled,
// arithmetic rel-pos bias index (no rpi gather).
// 1-D grid: total = 32 * ng blocks (ng = 12*cb groups), decode keeps each
// (bl,h) group of 32 m-blocks on one XCD assuming round-robin d%8 dispatch.
__global__ __launch_bounds__(256, 4) void loc_attn(const float* __restrict__ Q,
                                                   const float* __restrict__ K,
                                                   const float* __restrict__ V,
                                                   const float* __restrict__ rel,
                                                   const int* __restrict__ rand_idx,
                                                   float* __restrict__ out,
                                                   int b0, int ng) {
    // ---- XCD-contiguous decode (total divisible by 8 since 32*ng, ng=12*cb)
    int d = blockIdx.x;
    int xcd = d & 7, kk_ = d >> 3;
    int slot = xcd * (ng << 2) + kk_;      // ng*4 = total/8 blocks per XCD
    int g = slot >> 5;                      // group = h + 12*bl
    int m = slot & 31;
    int h = g % 12;
    int bl = g / 12;

    __shared__ float Qlds[52][64];      // rows 49..51 zero-filled
    __shared__ float Plds[4][13][64];   // per-wave P chunk transpose buffer
    __shared__ int   tok[320];          // 295 real + padding (token 0)
    int tid = threadIdx.x, lane = tid & 63, w = tid >> 6;

    size_t base = (size_t)((bl * 12 + h) * S_TOT) * 64;
    const float* Qb = Q + base;
    const float* Kb = K + base;
    const float* Vb = V + base;

    // stage token table (295 entries, pad to 320 with token 0)
    for (int jj = tid; jj < 320; jj += 256) {
        int t = 0;
        if (jj >= 1 && jj < 295) {
            int j1 = jj - 1;
            int n = j1 / 49;
            int q = j1 - n * 49;
            int a;
            if (n == 0)      a = (m + 31) & 31;
            else if (n == 1) a = m;
            else if (n == 2) a = (m + 1) & 31;
            else             a = rand_idx[m * 3 + (n - 3)];
            t = 1 + a * 49 + q;
        }
        tok[jj] = t;
    }
    // stage Q tile (49 rows + 3 zero rows), coalesced
    for (int idx = tid; idx < 52 * 64; idx += 256) {
        int r = idx >> 6, c = idx & 63;
        float qv = 0.f;
        if (r < 49) qv = Qb[(size_t)(1 + m * 49 + r) * 64 + c];
        ((float*)Qlds)[idx] = qv;
    }
    __syncthreads();

    // ---- per-row packed query coords cq[r] = zq*729 + yq*27 + xq
    // (wave-uniform; window 8x14x14, token p = z*196 + y*14 + x)
    int cq[13];
#pragma unroll
    for (int r = 0; r < 13; r++) {
        int i = w + 4 * r;
        int qr = 1 + m * 49 + i;
        if (qr > S_TOT - 1) qr = S_TOT - 1;   // clamp for pad rows 49..51
        int pq = qr - 1;
        int zq = pq / 196;
        int rem = pq - zq * 196;
        int yq = rem / 14;
        int xq = rem - yq * 14;
        cq[r] = zq * 729 + yq * 27 + xq;
    }

    float fm[13], fl[13], facc[13];
#pragma unroll
    for (int r = 0; r < 13; r++) { fm[r] = -1e30f; fl[r] = 0.f; facc[r] = 0.f; }

    for (int jc = 0; jc < 5; jc++) {
        int j = jc * 64 + lane;
        int tj = tok[j];
        const float* kp = Kb + (size_t)tj * 64;

        // per-lane packed key coords cj (tj==0 -> cls column, bidx=10936)
        int pj = tj - 1;
        int zj = pj / 196;
        int remj = pj - zj * 196;
        int yj = remj / 14;
        int xj = remj - yj * 14;
        int cj = zj * 729 + yj * 27 + xj;
        bool iscls = (tj == 0);

        // ---- QK^T for this 64-key chunk: s[r] = Q[i]·K[tj]
        float s[13];
#pragma unroll
        for (int r = 0; r < 13; r++) s[r] = 0.f;
#pragma unroll 4
        for (int d4 = 0; d4 < 16; d4++) {
            float4 kv = *(const float4*)(kp + d4 * 4);
#pragma unroll
            for (int r = 0; r < 13; r++) {
                float4 qv = *(const float4*)&Qlds[w + 4 * r][d4 * 4];   // broadcast
                s[r] = fmaf(qv.x, kv.x, s[r]);
                s[r] = fmaf(qv.y, kv.y, s[r]);
                s[r] = fmaf(qv.z, kv.z, s[r]);
                s[r] = fmaf(qv.w, kv.w, s[r]);
            }
        }

        // ---- bias + online softmax (per-row butterflies), write P chunk
        bool jv = j < 295;
#pragma unroll
        for (int r = 0; r < 13; r++) {
            // bidx = (dz+7)*729 + (dy+13)*27 + (dx+13) = cq - cj + 5467
            int bidx = iscls ? 10936 : (cq[r] - cj + 5467);
            float sv = jv ? fmaf(s[r], 0.125f, rel[bidx * 12 + h])
                          : -1e30f;
            float mx = sv;
#pragma unroll
            for (int off = 32; off > 0; off >>= 1) mx = fmaxf(mx, __shfl_xor(mx, off));
            float mnew = fmaxf(fm[r], mx);
            float p = __expf(sv - mnew);
            float alpha = __expf(fm[r] - mnew);
            fm[r] = mnew;
            float ps = p;
#pragma unroll
            for (int off = 32; off > 0; off >>= 1) ps += __shfl_xor(ps, off);
            fl[r] = fmaf(fl[r], alpha, ps);
            facc[r] *= alpha;
            Plds[w][r][lane] = p;
        }

        // ---- PV for this chunk: 4 keys per step, P via b128 broadcast
#pragma unroll 4
        for (int jg = 0; jg < 16; jg++) {
            int jb = jc * 64 + jg * 4;
            int t0 = tok[jb + 0], t1 = tok[jb + 1], t2 = tok[jb + 2], t3 = tok[jb + 3];
            float v0 = Vb[(size_t)t0 * 64 + lane];
            float v1 = Vb[(size_t)t1 * 64 + lane];
            float v2 = Vb[(size_t)t2 * 64 + lane];
            float v3 = Vb[(size_t)t3 * 64 + lane];
#pragma unroll
            for (int r = 0; r < 13; r++) {
                float4 p4 = *(const float4*)&Plds[w][r][jg * 4];        // broadcast
                facc[r] = fmaf(p4.x, v0, facc[r]);
                facc[r] = fmaf(p4.y, v1, facc[r]);
                facc[r] = fmaf(p4.z, v2, facc[r]);
                facc[r] = fmaf(p4.w, v3, facc[r]);
            }
        }
    }

    // ---- epilogue: normalize and store valid rows
    int nrows = (w == 0) ? 13 : 12;
    for (int r = 0; r < nrows; r++) {
        int i = w + 4 * r;
        int st = 1 + m * 49 + i;
        out[((size_t)(b0 + bl) * S_TOT + st) * 768 + h * 64 + lane] = facc[r] / fl[r];
    }
}

extern "C" void kernel_launch(void* const* d_in, const int* in_sizes, int n_in,
                              void* d_out, int out_size, void* d_ws, size_t ws_size,
                              hipStream_t stream) {
    (void)in_sizes; (void)n_in; (void)out_size;
    const float* hs  = (const float*)d_in[0];
    const float* Wq  = (const float*)d_in[1];
    const float* bq  = (const float*)d_in[2];
    const float* Wk  = (const float*)d_in[3];
    const float* Wv  = (const float*)d_in[4];
    const float* bv  = (const float*)d_in[5];
    const float* rel = (const float*)d_in[6];
    const int*   rpi = (const int*)d_in[7];
    const int*   rnd = (const int*)d_in[8];
    float* out = (float*)d_out;
    char* ws = (char*)d_ws;

    // ws layout: Q | K | V  (each C * PBUF bytes)
    constexpr size_t PBUF = (size_t)12 * S_TOT * 64 * 4;     // 4,819,968 per batch

    int C = 1;
    if (ws_size >= 3 * PBUF) {
        size_t c = ws_size / (3 * PBUF);
        C = (c >= NBATCH) ? NBATCH : (int)c;
        if (C < 1) C = 1;
    }
    float* Q = (float*)(ws);
    float* K = (float*)(ws + (size_t)C * PBUF);
    float* V = (float*)(ws + (size_t)C * PBUF * 2);

    for (int b0 = 0; b0 < NBATCH; b0 += C) {
        int cb = (NBATCH - b0 < C) ? (NBATCH - b0) : C;
        int nTok = cb * S_TOT;
        gemm_f32<<<dim3((nTok + 127) / 128, 18), dim3(256), 0, stream>>>(
            hs, Wq, Wk, Wv, bq, bv, Q, K, V, b0, nTok);
        cls_attn<<<dim3(12 * cb), dim3(256), 0, stream>>>(Q, K, V, rel, rpi, out, b0);
        int ngrp = 12 * cb;
        loc_attn<<<dim3(32 * ngrp), dim3(256), 0, stream>>>(
            Q, K, V, rel, rnd, out, b0, ngrp);
    }
}